// Round 6
// baseline (456.237 us; speedup 1.0000x reference)
//
#include <hip/hip_runtime.h>

#define D 128
#define BROWS 64
#define BSHIFT 6
#define COLBITS 17
#define COLMASK 0x1FFFF
#define CHUNKS 512
#define CAP 2560
#define CVTB 256

// ---------- Phase 1 (fused): per-chunk bucket histogram + emb fp32->bf16x2 ----------
// M[b * CHUNKS + c] = #edges of chunk c landing in bucket b
__global__ void k_prep(const int* __restrict__ rows, int E, int CE, int nb,
                       int* __restrict__ M,
                       const float2* __restrict__ emb, unsigned* __restrict__ q,
                       int n, int cvtb) {
    int histBlocks = gridDim.x - cvtb;
    if ((int)blockIdx.x >= histBlocks) {
        // conversion blocks
        int stride = cvtb * 256;
        for (int i = ((int)blockIdx.x - histBlocks) * 256 + threadIdx.x; i < n; i += stride) {
            float2 f = emb[i];
            unsigned lo = __float_as_uint(f.x), hi = __float_as_uint(f.y);
            lo = (lo + 0x7FFFu + ((lo >> 16) & 1u)) & 0xFFFF0000u;   // RNE to bf16
            hi = (hi + 0x7FFFu + ((hi >> 16) & 1u)) & 0xFFFF0000u;
            q[i] = hi | (lo >> 16);
        }
        return;
    }
    extern __shared__ int h[];
    int c = blockIdx.x;
    for (int i = threadIdx.x; i < nb; i += 256) h[i] = 0;
    __syncthreads();
    int beg = c * CE, end = min(E, beg + CE);
    for (int e = beg + threadIdx.x; e < end; e += 256)
        atomicAdd(&h[rows[e] >> BSHIFT], 1);
    __syncthreads();
    for (int i = threadIdx.x; i < nb; i += 256) M[(size_t)i * CHUNKS + c] = h[i];
}

// ---------- Phase 2: hierarchical exclusive scan (block-local O + block sums bs) ----------
__global__ void k_scan1(const int* __restrict__ M, int flat,
                        int* __restrict__ O, int* __restrict__ bs) {
    __shared__ int s[1024];
    int i = blockIdx.x * 1024 + threadIdx.x;
    int v = (i < flat) ? M[i] : 0;
    s[threadIdx.x] = v;
    __syncthreads();
    for (int off = 1; off < 1024; off <<= 1) {
        int t = (threadIdx.x >= (unsigned)off) ? s[threadIdx.x - off] : 0;
        __syncthreads();
        s[threadIdx.x] += t;
        __syncthreads();
    }
    if (i < flat) O[i] = s[threadIdx.x] - v;
    if (threadIdx.x == 1023) bs[blockIdx.x] = s[1023];
}

__global__ void k_scan2(int* __restrict__ bs, int nblk) {
    __shared__ int s[1024];
    __shared__ int carry;
    if (threadIdx.x == 0) carry = 0;
    __syncthreads();
    for (int base = 0; base < nblk; base += 1024) {
        int i = base + (int)threadIdx.x;
        int v = (i < nblk) ? bs[i] : 0;
        s[threadIdx.x] = v;
        __syncthreads();
        for (int off = 1; off < 1024; off <<= 1) {
            int t = (threadIdx.x >= (unsigned)off) ? s[threadIdx.x - off] : 0;
            __syncthreads();
            s[threadIdx.x] += t;
            __syncthreads();
        }
        int c = carry;
        if (i < nblk) bs[i] = c + s[threadIdx.x] - v;
        __syncthreads();
        if (threadIdx.x == 0) carry = c + s[1023];
        __syncthreads();
    }
}

// ---------- Phase 3: scatter via LDS cursors; final offset = O[f] + bs[f>>10] ----------
__global__ void k_mscatter(const int* __restrict__ rows, const int* __restrict__ cols,
                           const float* __restrict__ vals, int E, int CE, int nb,
                           const int* __restrict__ O, const int* __restrict__ bs,
                           unsigned long long* __restrict__ sorted) {
    extern __shared__ int cur[];
    int c = blockIdx.x;
    for (int b = threadIdx.x; b < nb; b += 256) {
        int f = b * CHUNKS + c;
        cur[b] = O[f] + bs[f >> 10];
    }
    __syncthreads();
    int beg = c * CE, end = min(E, beg + CE);
    for (int e = beg + threadIdx.x; e < end; e += 256) {
        int r = rows[e];
        int b = r >> BSHIFT;
        int pos = atomicAdd(&cur[b], 1);
        unsigned packed = ((unsigned)(r & (BROWS - 1)) << COLBITS) | (unsigned)cols[e];
        unsigned long long rec =
            ((unsigned long long)__float_as_uint(vals[e]) << 32) | (unsigned long long)packed;
        if (pos >= 0 && pos < E)                     // defensive: never write OOB
            __builtin_nontemporal_store(rec, sorted + pos);
    }
}

// ---------- Phase 4: per-bucket LDS counting sort + REGISTER accumulation ----------
template <bool BF16>
__global__ __launch_bounds__(256) void k_bucket2(const int2* __restrict__ sorted,
                                                 const int* __restrict__ O,
                                                 const int* __restrict__ bs,
                                                 const void* __restrict__ embp,
                                                 float* __restrict__ out,
                                                 int N, int nb, int E) {
    __shared__ int rowcnt[BROWS], rowoff[BROWS], rowcur[BROWS];
    __shared__ int2 rec2[CAP];
    int b  = blockIdx.x;
    int f0 = b * CHUNKS;
    int beg = O[f0] + bs[f0 >> 10];
    int end;
    if (b + 1 < nb) { int f1 = (b + 1) * CHUNKS; end = O[f1] + bs[f1 >> 10]; }
    else            end = E;
    // defensive clamps: a corrupted offset must not cause OOB reads
    beg = max(0, min(beg, E));
    end = max(beg, min(end, E));
    int wid = threadIdx.x >> 6, lane = threadIdx.x & 63;

    float2 acc[16];
#pragma unroll
    for (int q = 0; q < 16; ++q) acc[q] = make_float2(0.f, 0.f);

    const unsigned* eq = (const unsigned*)embp;
    const float2*   e2 = (const float2*)embp;

    for (int done = beg; done < end; done += CAP) {
        int cnt = min(CAP, end - done);
        if (threadIdx.x < BROWS) rowcnt[threadIdx.x] = 0;
        __syncthreads();
        for (int k = threadIdx.x; k < cnt; k += 256)
            atomicAdd(&rowcnt[(((unsigned)sorted[done + k].x) >> COLBITS) & (BROWS - 1)], 1);
        __syncthreads();
        if (threadIdx.x < 64) {
            int v = rowcnt[lane];
            int incl = v;
#pragma unroll
            for (int off = 1; off < 64; off <<= 1) {
                int u = __shfl_up(incl, off);
                if (lane >= off) incl += u;
            }
            rowoff[lane] = incl - v;
            rowcur[lane] = incl - v;
        }
        __syncthreads();
        for (int k = threadIdx.x; k < cnt; k += 256) {
            int2 r = sorted[done + k];
            int row = (((unsigned)r.x) >> COLBITS) & (BROWS - 1);
            int pos = atomicAdd(&rowcur[row], 1);
            if (pos >= 0 && pos < CAP) rec2[pos] = r;
        }
        __syncthreads();

#pragma unroll
        for (int q = 0; q < 16; ++q) {           // FULL unroll: acc stays in VGPRs
            int row = wid * 16 + q;
            int off = rowoff[row], cr = rowcnt[row];
            int j = 0;
            for (; j + 4 <= cr; j += 4) {
                int2 r0 = rec2[off + j], r1 = rec2[off + j + 1];
                int2 r2 = rec2[off + j + 2], r3 = rec2[off + j + 3];
                float v0 = __int_as_float(r0.y), v1 = __int_as_float(r1.y);
                float v2 = __int_as_float(r2.y), v3 = __int_as_float(r3.y);
                if (BF16) {
                    unsigned u0 = eq[(size_t)(r0.x & COLMASK) * 64 + lane];
                    unsigned u1 = eq[(size_t)(r1.x & COLMASK) * 64 + lane];
                    unsigned u2 = eq[(size_t)(r2.x & COLMASK) * 64 + lane];
                    unsigned u3 = eq[(size_t)(r3.x & COLMASK) * 64 + lane];
                    acc[q].x += v0 * __uint_as_float(u0 << 16);
                    acc[q].y += v0 * __uint_as_float(u0 & 0xFFFF0000u);
                    acc[q].x += v1 * __uint_as_float(u1 << 16);
                    acc[q].y += v1 * __uint_as_float(u1 & 0xFFFF0000u);
                    acc[q].x += v2 * __uint_as_float(u2 << 16);
                    acc[q].y += v2 * __uint_as_float(u2 & 0xFFFF0000u);
                    acc[q].x += v3 * __uint_as_float(u3 << 16);
                    acc[q].y += v3 * __uint_as_float(u3 & 0xFFFF0000u);
                } else {
                    float2 e0 = e2[(size_t)(r0.x & COLMASK) * 64 + lane];
                    float2 e1 = e2[(size_t)(r1.x & COLMASK) * 64 + lane];
                    float2 e3 = e2[(size_t)(r3.x & COLMASK) * 64 + lane];
                    float2 e2v = e2[(size_t)(r2.x & COLMASK) * 64 + lane];
                    acc[q].x += v0 * e0.x;  acc[q].y += v0 * e0.y;
                    acc[q].x += v1 * e1.x;  acc[q].y += v1 * e1.y;
                    acc[q].x += v2 * e2v.x; acc[q].y += v2 * e2v.y;
                    acc[q].x += v3 * e3.x;  acc[q].y += v3 * e3.y;
                }
            }
            for (; j < cr; ++j) {
                int2 r0 = rec2[off + j];
                float v0 = __int_as_float(r0.y);
                if (BF16) {
                    unsigned u0 = eq[(size_t)(r0.x & COLMASK) * 64 + lane];
                    acc[q].x += v0 * __uint_as_float(u0 << 16);
                    acc[q].y += v0 * __uint_as_float(u0 & 0xFFFF0000u);
                } else {
                    float2 e0 = e2[(size_t)(r0.x & COLMASK) * 64 + lane];
                    acc[q].x += v0 * e0.x;
                    acc[q].y += v0 * e0.y;
                }
            }
        }
        __syncthreads();
    }

    // nontemporal output stores: out is never re-read; keep L2 for emb gathers
    size_t rowbase = (size_t)b * BROWS;
    unsigned long long* out64 = (unsigned long long*)out;
#pragma unroll
    for (int q = 0; q < 16; ++q) {
        size_t row = rowbase + wid * 16 + q;
        if (row < (size_t)N) {
            unsigned long long p =
                ((unsigned long long)__float_as_uint(acc[q].y) << 32) |
                (unsigned long long)__float_as_uint(acc[q].x);
            __builtin_nontemporal_store(p, out64 + row * 64 + lane);
        }
    }
}

// ---------- Fallback: direct atomic scatter-add ----------
__global__ void k_atomic(const int* __restrict__ rows, const int* __restrict__ cols,
                         const float* __restrict__ vals, const float2* __restrict__ emb,
                         float* __restrict__ out, int E) {
    long long g = (long long)blockIdx.x * blockDim.x + threadIdx.x;
    int e    = (int)(g >> 6);
    int lane = (int)(g & 63);
    if (e >= E) return;
    int r = rows[e], c = cols[e];
    float v = vals[e];
    float2 em = emb[(size_t)c * (D / 2) + lane];
    atomicAdd(&out[(size_t)r * D + lane * 2    ], v * em.x);
    atomicAdd(&out[(size_t)r * D + lane * 2 + 1], v * em.y);
}

extern "C" void kernel_launch(void* const* d_in, const int* in_sizes, int n_in,
                              void* d_out, int out_size, void* d_ws, size_t ws_size,
                              hipStream_t stream) {
    const int*   adj  = (const int*)d_in[0];
    const float* vals = (const float*)d_in[1];
    const float* emb  = (const float*)d_in[2];
    int E = in_sizes[1];
    int N = in_sizes[2] / D;
    const int* rows = adj;
    const int* cols = adj + E;
    float* out = (float*)d_out;

    int nb   = (N + BROWS - 1) / BROWS;
    int CE   = (E + CHUNKS - 1) / CHUNKS;
    int flat = nb * CHUNKS;
    int nblk = (flat + 1023) / 1024;

    size_t off_sorted = 0;
    size_t sz_sorted  = (size_t)E * 8;
    size_t off_M      = (off_sorted + sz_sorted + 255) & ~(size_t)255;
    size_t sz_M       = (size_t)flat * 4;
    size_t off_O      = (off_M + sz_M + 255) & ~(size_t)255;
    size_t sz_O       = (size_t)flat * 4;
    size_t off_bs     = (off_O + sz_O + 255) & ~(size_t)255;
    size_t sz_bs      = (size_t)nblk * 4;
    size_t off_q      = (off_bs + sz_bs + 255) & ~(size_t)255;
    size_t sz_q       = (size_t)N * 64 * 4;
    size_t need_bf16  = off_q + sz_q;
    size_t need_f32   = off_q;

    bool ok = (N <= (1 << COLBITS)) && ((size_t)nb * 4 <= 65536);

    if (ok && ws_size >= need_f32) {
        char* ws = (char*)d_ws;
        unsigned long long* sorted = (unsigned long long*)(ws + off_sorted);
        int* M  = (int*)(ws + off_M);
        int* O  = (int*)(ws + off_O);
        int* bs = (int*)(ws + off_bs);
        bool bf16 = (ws_size >= need_bf16);
        unsigned* q = (unsigned*)(ws + off_q);

        int cvtb = bf16 ? CVTB : 0;
        k_prep    <<<CHUNKS + cvtb, 256, (size_t)nb * 4, stream>>>(
                      rows, E, CE, nb, M, (const float2*)emb, q, N * 64, cvtb);
        k_scan1   <<<nblk, 1024, 0, stream>>>(M, flat, O, bs);
        k_scan2   <<<1, 1024, 0, stream>>>(bs, nblk);
        k_mscatter<<<CHUNKS, 256, (size_t)nb * 4, stream>>>(
                      rows, cols, vals, E, CE, nb, O, bs, sorted);
        if (bf16) {
            k_bucket2<true><<<nb, 256, 0, stream>>>((const int2*)sorted, O, bs,
                                                    (const void*)q, out, N, nb, E);
        } else {
            k_bucket2<false><<<nb, 256, 0, stream>>>((const int2*)sorted, O, bs,
                                                     (const void*)emb, out, N, nb, E);
        }
    } else {
        hipMemsetAsync(out, 0, (size_t)out_size * sizeof(float), stream);
        long long tot = (long long)E * 64;
        int blocks = (int)((tot + 255) / 256);
        k_atomic<<<blocks, 256, 0, stream>>>(rows, cols, vals, (const float2*)emb, out, E);
    }
}

// Round 7
// 353.083 us; speedup vs baseline: 1.2922x; 1.2922x over previous
//
#include <hip/hip_runtime.h>

#define D 128
#define BROWS 32
#define BSHIFT 5
#define COLBITS 17
#define COLMASK 0x1FFFF
#define CHUNKS 256
#define CAP 1280
#define CVTB 64
#define PBLK 1024

// ---------- Phase 1 (fused): per-chunk bucket histogram + emb fp32->bf16x2 ----------
// M[b * CHUNKS + c] = #edges of chunk c landing in bucket b
__global__ void k_prep(const int* __restrict__ rows, int E, int CE, int nb,
                       int* __restrict__ M,
                       const float2* __restrict__ emb, unsigned* __restrict__ q,
                       int n, int cvtb) {
    int histBlocks = gridDim.x - cvtb;
    if ((int)blockIdx.x >= histBlocks) {
        int stride = cvtb * PBLK;
        for (int i = ((int)blockIdx.x - histBlocks) * PBLK + threadIdx.x; i < n; i += stride) {
            float2 f = emb[i];
            unsigned lo = __float_as_uint(f.x), hi = __float_as_uint(f.y);
            lo = (lo + 0x7FFFu + ((lo >> 16) & 1u)) & 0xFFFF0000u;   // RNE to bf16
            hi = (hi + 0x7FFFu + ((hi >> 16) & 1u)) & 0xFFFF0000u;
            q[i] = hi | (lo >> 16);
        }
        return;
    }
    extern __shared__ int h[];
    int c = blockIdx.x;
    for (int i = threadIdx.x; i < nb; i += PBLK) h[i] = 0;
    __syncthreads();
    int beg = c * CE, end = min(E, beg + CE);
    for (int e = beg + threadIdx.x; e < end; e += PBLK)
        atomicAdd(&h[rows[e] >> BSHIFT], 1);
    __syncthreads();
    for (int i = threadIdx.x; i < nb; i += PBLK) M[(size_t)i * CHUNKS + c] = h[i];
}

// ---------- Phase 2: hierarchical exclusive scan (block-local O + block sums bs) ----------
__global__ void k_scan1(const int* __restrict__ M, int flat,
                        int* __restrict__ O, int* __restrict__ bs) {
    __shared__ int s[1024];
    int i = blockIdx.x * 1024 + threadIdx.x;
    int v = (i < flat) ? M[i] : 0;
    s[threadIdx.x] = v;
    __syncthreads();
    for (int off = 1; off < 1024; off <<= 1) {
        int t = (threadIdx.x >= (unsigned)off) ? s[threadIdx.x - off] : 0;
        __syncthreads();
        s[threadIdx.x] += t;
        __syncthreads();
    }
    if (i < flat) O[i] = s[threadIdx.x] - v;
    if (threadIdx.x == 1023) bs[blockIdx.x] = s[1023];
}

__global__ void k_scan2(int* __restrict__ bs, int nblk) {
    __shared__ int s[1024];
    __shared__ int carry;
    if (threadIdx.x == 0) carry = 0;
    __syncthreads();
    for (int base = 0; base < nblk; base += 1024) {
        int i = base + (int)threadIdx.x;
        int v = (i < nblk) ? bs[i] : 0;
        s[threadIdx.x] = v;
        __syncthreads();
        for (int off = 1; off < 1024; off <<= 1) {
            int t = (threadIdx.x >= (unsigned)off) ? s[threadIdx.x - off] : 0;
            __syncthreads();
            s[threadIdx.x] += t;
            __syncthreads();
        }
        int c = carry;
        if (i < nblk) bs[i] = c + s[threadIdx.x] - v;
        __syncthreads();
        if (threadIdx.x == 0) carry = c + s[1023];
        __syncthreads();
    }
}

// ---------- Phase 3: scatter via LDS cursors; final offset = O[f] + bs[f>>10] ----------
__global__ void k_mscatter(const int* __restrict__ rows, const int* __restrict__ cols,
                           const float* __restrict__ vals, int E, int CE, int nb,
                           const int* __restrict__ O, const int* __restrict__ bs,
                           unsigned long long* __restrict__ sorted) {
    extern __shared__ int cur[];
    int c = blockIdx.x;
    for (int b = threadIdx.x; b < nb; b += PBLK) {
        int f = b * CHUNKS + c;
        cur[b] = O[f] + bs[f >> 10];
    }
    __syncthreads();
    int beg = c * CE, end = min(E, beg + CE);
    for (int e = beg + threadIdx.x; e < end; e += PBLK) {
        int r = rows[e];
        int b = r >> BSHIFT;
        int pos = atomicAdd(&cur[b], 1);
        unsigned packed = ((unsigned)(r & (BROWS - 1)) << COLBITS) | (unsigned)cols[e];
        unsigned long long rec =
            ((unsigned long long)__float_as_uint(vals[e]) << 32) | (unsigned long long)packed;
        if (pos >= 0 && pos < E)                     // normal store: L2 aggregates lines
            sorted[pos] = rec;
    }
}

// ---------- Phase 4: per-bucket LDS counting sort + REGISTER accumulation ----------
#define GATHER(idx) \
    int2 r##idx = rec2[off + j + idx]; \
    float v##idx = __int_as_float(r##idx.y);

template <bool BF16>
__global__ __launch_bounds__(256) void k_bucket2(const int2* __restrict__ sorted,
                                                 const int* __restrict__ O,
                                                 const int* __restrict__ bs,
                                                 const void* __restrict__ embp,
                                                 float* __restrict__ out,
                                                 int N, int nb, int E) {
    __shared__ int rowcnt[BROWS], rowoff[BROWS], rowcur[BROWS];
    __shared__ int2 rec2[CAP];
    int b  = blockIdx.x;
    int f0 = b * CHUNKS;
    int beg = O[f0] + bs[f0 >> 10];
    int end;
    if (b + 1 < nb) { int f1 = (b + 1) * CHUNKS; end = O[f1] + bs[f1 >> 10]; }
    else            end = E;
    beg = max(0, min(beg, E));
    end = max(beg, min(end, E));
    int wid = threadIdx.x >> 6, lane = threadIdx.x & 63;

    float2 acc[8];
#pragma unroll
    for (int q = 0; q < 8; ++q) acc[q] = make_float2(0.f, 0.f);

    const unsigned* eq = (const unsigned*)embp;
    const float2*   e2 = (const float2*)embp;

    for (int done = beg; done < end; done += CAP) {
        int cnt = min(CAP, end - done);
        if (threadIdx.x < BROWS) rowcnt[threadIdx.x] = 0;
        __syncthreads();
        for (int k = threadIdx.x; k < cnt; k += 256)
            atomicAdd(&rowcnt[(((unsigned)sorted[done + k].x) >> COLBITS) & (BROWS - 1)], 1);
        __syncthreads();
        if (threadIdx.x < BROWS) {
            int v = rowcnt[threadIdx.x];
            int incl = v;
#pragma unroll
            for (int off = 1; off < BROWS; off <<= 1) {
                int u = __shfl_up(incl, off);
                if ((int)threadIdx.x >= off) incl += u;
            }
            rowoff[threadIdx.x] = incl - v;
            rowcur[threadIdx.x] = incl - v;
        }
        __syncthreads();
        for (int k = threadIdx.x; k < cnt; k += 256) {
            int2 r = sorted[done + k];
            int row = (((unsigned)r.x) >> COLBITS) & (BROWS - 1);
            int pos = atomicAdd(&rowcur[row], 1);
            if (pos >= 0 && pos < CAP) rec2[pos] = r;
        }
        __syncthreads();

#pragma unroll
        for (int q = 0; q < 8; ++q) {            // 8 rows/wave: acc stays in VGPRs
            int row = wid * 8 + q;
            int off = rowoff[row], cr = rowcnt[row];
            int j = 0;
            for (; j + 8 <= cr; j += 8) {        // 8 outstanding gathers
                GATHER(0) GATHER(1) GATHER(2) GATHER(3)
                GATHER(4) GATHER(5) GATHER(6) GATHER(7)
                if (BF16) {
                    unsigned u0 = eq[(size_t)(r0.x & COLMASK) * 64 + lane];
                    unsigned u1 = eq[(size_t)(r1.x & COLMASK) * 64 + lane];
                    unsigned u2 = eq[(size_t)(r2.x & COLMASK) * 64 + lane];
                    unsigned u3 = eq[(size_t)(r3.x & COLMASK) * 64 + lane];
                    unsigned u4 = eq[(size_t)(r4.x & COLMASK) * 64 + lane];
                    unsigned u5 = eq[(size_t)(r5.x & COLMASK) * 64 + lane];
                    unsigned u6 = eq[(size_t)(r6.x & COLMASK) * 64 + lane];
                    unsigned u7 = eq[(size_t)(r7.x & COLMASK) * 64 + lane];
                    acc[q].x += v0 * __uint_as_float(u0 << 16);
                    acc[q].y += v0 * __uint_as_float(u0 & 0xFFFF0000u);
                    acc[q].x += v1 * __uint_as_float(u1 << 16);
                    acc[q].y += v1 * __uint_as_float(u1 & 0xFFFF0000u);
                    acc[q].x += v2 * __uint_as_float(u2 << 16);
                    acc[q].y += v2 * __uint_as_float(u2 & 0xFFFF0000u);
                    acc[q].x += v3 * __uint_as_float(u3 << 16);
                    acc[q].y += v3 * __uint_as_float(u3 & 0xFFFF0000u);
                    acc[q].x += v4 * __uint_as_float(u4 << 16);
                    acc[q].y += v4 * __uint_as_float(u4 & 0xFFFF0000u);
                    acc[q].x += v5 * __uint_as_float(u5 << 16);
                    acc[q].y += v5 * __uint_as_float(u5 & 0xFFFF0000u);
                    acc[q].x += v6 * __uint_as_float(u6 << 16);
                    acc[q].y += v6 * __uint_as_float(u6 & 0xFFFF0000u);
                    acc[q].x += v7 * __uint_as_float(u7 << 16);
                    acc[q].y += v7 * __uint_as_float(u7 & 0xFFFF0000u);
                } else {
                    float2 e0 = e2[(size_t)(r0.x & COLMASK) * 64 + lane];
                    float2 e1 = e2[(size_t)(r1.x & COLMASK) * 64 + lane];
                    float2 e2v = e2[(size_t)(r2.x & COLMASK) * 64 + lane];
                    float2 e3 = e2[(size_t)(r3.x & COLMASK) * 64 + lane];
                    float2 e4 = e2[(size_t)(r4.x & COLMASK) * 64 + lane];
                    float2 e5 = e2[(size_t)(r5.x & COLMASK) * 64 + lane];
                    float2 e6 = e2[(size_t)(r6.x & COLMASK) * 64 + lane];
                    float2 e7 = e2[(size_t)(r7.x & COLMASK) * 64 + lane];
                    acc[q].x += v0 * e0.x;  acc[q].y += v0 * e0.y;
                    acc[q].x += v1 * e1.x;  acc[q].y += v1 * e1.y;
                    acc[q].x += v2 * e2v.x; acc[q].y += v2 * e2v.y;
                    acc[q].x += v3 * e3.x;  acc[q].y += v3 * e3.y;
                    acc[q].x += v4 * e4.x;  acc[q].y += v4 * e4.y;
                    acc[q].x += v5 * e5.x;  acc[q].y += v5 * e5.y;
                    acc[q].x += v6 * e6.x;  acc[q].y += v6 * e6.y;
                    acc[q].x += v7 * e7.x;  acc[q].y += v7 * e7.y;
                }
            }
            for (; j < cr; ++j) {
                int2 r0 = rec2[off + j];
                float v0 = __int_as_float(r0.y);
                if (BF16) {
                    unsigned u0 = eq[(size_t)(r0.x & COLMASK) * 64 + lane];
                    acc[q].x += v0 * __uint_as_float(u0 << 16);
                    acc[q].y += v0 * __uint_as_float(u0 & 0xFFFF0000u);
                } else {
                    float2 e0 = e2[(size_t)(r0.x & COLMASK) * 64 + lane];
                    acc[q].x += v0 * e0.x;
                    acc[q].y += v0 * e0.y;
                }
            }
        }
        __syncthreads();
    }

    // nontemporal output stores: out is never re-read; keep L2 for emb gathers
    size_t rowbase = (size_t)b * BROWS;
    unsigned long long* out64 = (unsigned long long*)out;
#pragma unroll
    for (int q = 0; q < 8; ++q) {
        size_t row = rowbase + wid * 8 + q;
        if (row < (size_t)N) {
            unsigned long long p =
                ((unsigned long long)__float_as_uint(acc[q].y) << 32) |
                (unsigned long long)__float_as_uint(acc[q].x);
            __builtin_nontemporal_store(p, out64 + row * 64 + lane);
        }
    }
}

// ---------- Fallback: direct atomic scatter-add ----------
__global__ void k_atomic(const int* __restrict__ rows, const int* __restrict__ cols,
                         const float* __restrict__ vals, const float2* __restrict__ emb,
                         float* __restrict__ out, int E) {
    long long g = (long long)blockIdx.x * blockDim.x + threadIdx.x;
    int e    = (int)(g >> 6);
    int lane = (int)(g & 63);
    if (e >= E) return;
    int r = rows[e], c = cols[e];
    float v = vals[e];
    float2 em = emb[(size_t)c * (D / 2) + lane];
    atomicAdd(&out[(size_t)r * D + lane * 2    ], v * em.x);
    atomicAdd(&out[(size_t)r * D + lane * 2 + 1], v * em.y);
}

extern "C" void kernel_launch(void* const* d_in, const int* in_sizes, int n_in,
                              void* d_out, int out_size, void* d_ws, size_t ws_size,
                              hipStream_t stream) {
    const int*   adj  = (const int*)d_in[0];
    const float* vals = (const float*)d_in[1];
    const float* emb  = (const float*)d_in[2];
    int E = in_sizes[1];
    int N = in_sizes[2] / D;
    const int* rows = adj;
    const int* cols = adj + E;
    float* out = (float*)d_out;

    int nb   = (N + BROWS - 1) / BROWS;
    int CE   = (E + CHUNKS - 1) / CHUNKS;
    int flat = nb * CHUNKS;
    int nblk = (flat + 1023) / 1024;

    size_t off_sorted = 0;
    size_t sz_sorted  = (size_t)E * 8;
    size_t off_M      = (off_sorted + sz_sorted + 255) & ~(size_t)255;
    size_t sz_M       = (size_t)flat * 4;
    size_t off_O      = (off_M + sz_M + 255) & ~(size_t)255;
    size_t sz_O       = (size_t)flat * 4;
    size_t off_bs     = (off_O + sz_O + 255) & ~(size_t)255;
    size_t sz_bs      = (size_t)nblk * 4;
    size_t off_q      = (off_bs + sz_bs + 255) & ~(size_t)255;
    size_t sz_q       = (size_t)N * 64 * 4;
    size_t need_bf16  = off_q + sz_q;
    size_t need_f32   = off_q;

    bool ok = (N <= (1 << COLBITS)) && ((size_t)nb * 4 <= 60000) && (nblk <= 1024);

    if (ok && ws_size >= need_f32) {
        char* ws = (char*)d_ws;
        unsigned long long* sorted = (unsigned long long*)(ws + off_sorted);
        int* M  = (int*)(ws + off_M);
        int* O  = (int*)(ws + off_O);
        int* bs = (int*)(ws + off_bs);
        bool bf16 = (ws_size >= need_bf16);
        unsigned* q = (unsigned*)(ws + off_q);

        int cvtb = bf16 ? CVTB : 0;
        k_prep    <<<CHUNKS + cvtb, PBLK, (size_t)nb * 4, stream>>>(
                      rows, E, CE, nb, M, (const float2*)emb, q, N * 64, cvtb);
        k_scan1   <<<nblk, 1024, 0, stream>>>(M, flat, O, bs);
        k_scan2   <<<1, 1024, 0, stream>>>(bs, nblk);
        k_mscatter<<<CHUNKS, PBLK, (size_t)nb * 4, stream>>>(
                      rows, cols, vals, E, CE, nb, O, bs, sorted);
        if (bf16) {
            k_bucket2<true><<<nb, 256, 0, stream>>>((const int2*)sorted, O, bs,
                                                    (const void*)q, out, N, nb, E);
        } else {
            k_bucket2<false><<<nb, 256, 0, stream>>>((const int2*)sorted, O, bs,
                                                     (const void*)emb, out, N, nb, E);
        }
    } else {
        hipMemsetAsync(out, 0, (size_t)out_size * sizeof(float), stream);
        long long tot = (long long)E * 64;
        int blocks = (int)((tot + 255) / 256);
        k_atomic<<<blocks, 256, 0, stream>>>(rows, cols, vals, (const float2*)emb, out, E);
    }
}

// Round 8
// 334.137 us; speedup vs baseline: 1.3654x; 1.0567x over previous
//
#include <hip/hip_runtime.h>

#define D 128
#define BROWS 32
#define BSHIFT 5
#define COLBITS 17
#define COLMASK 0x1FFFF
#define CHUNKS 256
#define CAP 1280
#define MAXR 5          // CAP / 256
#define CVTB 1792
#define PBLK 1024

// ---------- Phase 1 (fused): per-chunk bucket histogram + emb fp32->bf16x2 ----------
// M[b * CHUNKS + c] = #edges of chunk c landing in bucket b
__global__ void k_prep(const int* __restrict__ rows, int E, int CE, int nb,
                       int* __restrict__ M,
                       const float2* __restrict__ emb, unsigned* __restrict__ q,
                       int n, int cvtb) {
    int histBlocks = gridDim.x - cvtb;
    if ((int)blockIdx.x >= histBlocks) {
        int stride = cvtb * PBLK;
        for (int i = ((int)blockIdx.x - histBlocks) * PBLK + threadIdx.x; i < n; i += stride) {
            float2 f = emb[i];
            unsigned lo = __float_as_uint(f.x), hi = __float_as_uint(f.y);
            lo = (lo + 0x7FFFu + ((lo >> 16) & 1u)) & 0xFFFF0000u;   // RNE to bf16
            hi = (hi + 0x7FFFu + ((hi >> 16) & 1u)) & 0xFFFF0000u;
            q[i] = hi | (lo >> 16);
        }
        return;
    }
    extern __shared__ int h[];
    int c = blockIdx.x;
    for (int i = threadIdx.x; i < nb; i += PBLK) h[i] = 0;
    __syncthreads();
    int beg = c * CE, end = min(E, beg + CE);
    for (int e = beg + threadIdx.x; e < end; e += PBLK)
        atomicAdd(&h[rows[e] >> BSHIFT], 1);
    __syncthreads();
    for (int i = threadIdx.x; i < nb; i += PBLK) M[(size_t)i * CHUNKS + c] = h[i];
}

// ---------- Phase 2: hierarchical exclusive scan (block-local O + block sums bs) ----------
__global__ void k_scan1(const int* __restrict__ M, int flat,
                        int* __restrict__ O, int* __restrict__ bs) {
    __shared__ int s[1024];
    int i = blockIdx.x * 1024 + threadIdx.x;
    int v = (i < flat) ? M[i] : 0;
    s[threadIdx.x] = v;
    __syncthreads();
    for (int off = 1; off < 1024; off <<= 1) {
        int t = (threadIdx.x >= (unsigned)off) ? s[threadIdx.x - off] : 0;
        __syncthreads();
        s[threadIdx.x] += t;
        __syncthreads();
    }
    if (i < flat) O[i] = s[threadIdx.x] - v;
    if (threadIdx.x == 1023) bs[blockIdx.x] = s[1023];
}

__global__ void k_scan2(int* __restrict__ bs, int nblk) {
    __shared__ int s[1024];
    __shared__ int carry;
    if (threadIdx.x == 0) carry = 0;
    __syncthreads();
    for (int base = 0; base < nblk; base += 1024) {
        int i = base + (int)threadIdx.x;
        int v = (i < nblk) ? bs[i] : 0;
        s[threadIdx.x] = v;
        __syncthreads();
        for (int off = 1; off < 1024; off <<= 1) {
            int t = (threadIdx.x >= (unsigned)off) ? s[threadIdx.x - off] : 0;
            __syncthreads();
            s[threadIdx.x] += t;
            __syncthreads();
        }
        int c = carry;
        if (i < nblk) bs[i] = c + s[threadIdx.x] - v;
        __syncthreads();
        if (threadIdx.x == 0) carry = c + s[1023];
        __syncthreads();
    }
}

// ---------- Phase 3: scatter via LDS cursors; final offset = O[f] + bs[f>>10] ----------
__global__ void k_mscatter(const int* __restrict__ rows, const int* __restrict__ cols,
                           const float* __restrict__ vals, int E, int CE, int nb,
                           const int* __restrict__ O, const int* __restrict__ bs,
                           unsigned long long* __restrict__ sorted) {
    extern __shared__ int cur[];
    int c = blockIdx.x;
    for (int b = threadIdx.x; b < nb; b += PBLK) {
        int f = b * CHUNKS + c;
        cur[b] = O[f] + bs[f >> 10];
    }
    __syncthreads();
    int beg = c * CE, end = min(E, beg + CE);
    for (int e = beg + threadIdx.x; e < end; e += PBLK) {
        int r = rows[e];
        int b = r >> BSHIFT;
        int pos = atomicAdd(&cur[b], 1);
        unsigned packed = ((unsigned)(r & (BROWS - 1)) << COLBITS) | (unsigned)cols[e];
        unsigned long long rec =
            ((unsigned long long)__float_as_uint(vals[e]) << 32) | (unsigned long long)packed;
        if (pos >= 0 && pos < E)                     // normal store: L2 aggregates lines
            sorted[pos] = rec;
    }
}

// ---------- Phase 4: per-bucket LDS counting sort + REGISTER accumulation ----------
#define GATHER(idx) \
    int2 r##idx = rec2[off + j + idx]; \
    float v##idx = __int_as_float(r##idx.y);

template <bool BF16>
__global__ __launch_bounds__(256) void k_bucket2(const int2* __restrict__ sorted,
                                                 const int* __restrict__ O,
                                                 const int* __restrict__ bs,
                                                 const void* __restrict__ embp,
                                                 float* __restrict__ out,
                                                 int N, int nb, int E) {
    __shared__ int rowcnt[BROWS], rowoff[BROWS], rowcur[BROWS];
    __shared__ int2 rec2[CAP];
    int b  = blockIdx.x;
    int f0 = b * CHUNKS;
    int beg = O[f0] + bs[f0 >> 10];
    int end;
    if (b + 1 < nb) { int f1 = (b + 1) * CHUNKS; end = O[f1] + bs[f1 >> 10]; }
    else            end = E;
    beg = max(0, min(beg, E));
    end = max(beg, min(end, E));
    int wid = threadIdx.x >> 6, lane = threadIdx.x & 63;

    float2 acc[8];
#pragma unroll
    for (int q = 0; q < 8; ++q) acc[q] = make_float2(0.f, 0.f);

    const unsigned* eq = (const unsigned*)embp;
    const float2*   e2 = (const float2*)embp;

    for (int done = beg; done < end; done += CAP) {
        int cnt = min(CAP, end - done);
        if (threadIdx.x < BROWS) rowcnt[threadIdx.x] = 0;
        __syncthreads();

        // single global read of this chunk's records into registers
        int2 rr[MAXR];
#pragma unroll
        for (int t = 0; t < MAXR; ++t) {
            int k = (int)threadIdx.x + t * 256;
            rr[t] = (k < cnt) ? sorted[done + k] : make_int2(-1, 0);
        }
#pragma unroll
        for (int t = 0; t < MAXR; ++t)
            if (rr[t].x >= 0)
                atomicAdd(&rowcnt[(((unsigned)rr[t].x) >> COLBITS) & (BROWS - 1)], 1);
        __syncthreads();
        if (threadIdx.x < BROWS) {
            int v = rowcnt[threadIdx.x];
            int incl = v;
#pragma unroll
            for (int off = 1; off < BROWS; off <<= 1) {
                int u = __shfl_up(incl, off);
                if ((int)threadIdx.x >= off) incl += u;
            }
            rowoff[threadIdx.x] = incl - v;
            rowcur[threadIdx.x] = incl - v;
        }
        __syncthreads();
#pragma unroll
        for (int t = 0; t < MAXR; ++t) {
            if (rr[t].x >= 0) {
                int row = (((unsigned)rr[t].x) >> COLBITS) & (BROWS - 1);
                int pos = atomicAdd(&rowcur[row], 1);
                if (pos >= 0 && pos < CAP) rec2[pos] = rr[t];
            }
        }
        __syncthreads();

#pragma unroll
        for (int q = 0; q < 8; ++q) {            // 8 rows/wave: acc stays in VGPRs
            int row = wid * 8 + q;
            int off = rowoff[row], cr = rowcnt[row];
            int j = 0;
            for (; j + 8 <= cr; j += 8) {        // 8 outstanding gathers
                GATHER(0) GATHER(1) GATHER(2) GATHER(3)
                GATHER(4) GATHER(5) GATHER(6) GATHER(7)
                if (BF16) {
                    unsigned u0 = eq[(size_t)(r0.x & COLMASK) * 64 + lane];
                    unsigned u1 = eq[(size_t)(r1.x & COLMASK) * 64 + lane];
                    unsigned u2 = eq[(size_t)(r2.x & COLMASK) * 64 + lane];
                    unsigned u3 = eq[(size_t)(r3.x & COLMASK) * 64 + lane];
                    unsigned u4 = eq[(size_t)(r4.x & COLMASK) * 64 + lane];
                    unsigned u5 = eq[(size_t)(r5.x & COLMASK) * 64 + lane];
                    unsigned u6 = eq[(size_t)(r6.x & COLMASK) * 64 + lane];
                    unsigned u7 = eq[(size_t)(r7.x & COLMASK) * 64 + lane];
                    acc[q].x += v0 * __uint_as_float(u0 << 16);
                    acc[q].y += v0 * __uint_as_float(u0 & 0xFFFF0000u);
                    acc[q].x += v1 * __uint_as_float(u1 << 16);
                    acc[q].y += v1 * __uint_as_float(u1 & 0xFFFF0000u);
                    acc[q].x += v2 * __uint_as_float(u2 << 16);
                    acc[q].y += v2 * __uint_as_float(u2 & 0xFFFF0000u);
                    acc[q].x += v3 * __uint_as_float(u3 << 16);
                    acc[q].y += v3 * __uint_as_float(u3 & 0xFFFF0000u);
                    acc[q].x += v4 * __uint_as_float(u4 << 16);
                    acc[q].y += v4 * __uint_as_float(u4 & 0xFFFF0000u);
                    acc[q].x += v5 * __uint_as_float(u5 << 16);
                    acc[q].y += v5 * __uint_as_float(u5 & 0xFFFF0000u);
                    acc[q].x += v6 * __uint_as_float(u6 << 16);
                    acc[q].y += v6 * __uint_as_float(u6 & 0xFFFF0000u);
                    acc[q].x += v7 * __uint_as_float(u7 << 16);
                    acc[q].y += v7 * __uint_as_float(u7 & 0xFFFF0000u);
                } else {
                    float2 e0 = e2[(size_t)(r0.x & COLMASK) * 64 + lane];
                    float2 e1 = e2[(size_t)(r1.x & COLMASK) * 64 + lane];
                    float2 e2v = e2[(size_t)(r2.x & COLMASK) * 64 + lane];
                    float2 e3 = e2[(size_t)(r3.x & COLMASK) * 64 + lane];
                    float2 e4 = e2[(size_t)(r4.x & COLMASK) * 64 + lane];
                    float2 e5 = e2[(size_t)(r5.x & COLMASK) * 64 + lane];
                    float2 e6 = e2[(size_t)(r6.x & COLMASK) * 64 + lane];
                    float2 e7 = e2[(size_t)(r7.x & COLMASK) * 64 + lane];
                    acc[q].x += v0 * e0.x;  acc[q].y += v0 * e0.y;
                    acc[q].x += v1 * e1.x;  acc[q].y += v1 * e1.y;
                    acc[q].x += v2 * e2v.x; acc[q].y += v2 * e2v.y;
                    acc[q].x += v3 * e3.x;  acc[q].y += v3 * e3.y;
                    acc[q].x += v4 * e4.x;  acc[q].y += v4 * e4.y;
                    acc[q].x += v5 * e5.x;  acc[q].y += v5 * e5.y;
                    acc[q].x += v6 * e6.x;  acc[q].y += v6 * e6.y;
                    acc[q].x += v7 * e7.x;  acc[q].y += v7 * e7.y;
                }
            }
            for (; j < cr; ++j) {
                int2 r0 = rec2[off + j];
                float v0 = __int_as_float(r0.y);
                if (BF16) {
                    unsigned u0 = eq[(size_t)(r0.x & COLMASK) * 64 + lane];
                    acc[q].x += v0 * __uint_as_float(u0 << 16);
                    acc[q].y += v0 * __uint_as_float(u0 & 0xFFFF0000u);
                } else {
                    float2 e0 = e2[(size_t)(r0.x & COLMASK) * 64 + lane];
                    acc[q].x += v0 * e0.x;
                    acc[q].y += v0 * e0.y;
                }
            }
        }
        __syncthreads();
    }

    // nontemporal output stores: out is never re-read; keep L2 for emb gathers
    size_t rowbase = (size_t)b * BROWS;
    unsigned long long* out64 = (unsigned long long*)out;
#pragma unroll
    for (int q = 0; q < 8; ++q) {
        size_t row = rowbase + wid * 8 + q;
        if (row < (size_t)N) {
            unsigned long long p =
                ((unsigned long long)__float_as_uint(acc[q].y) << 32) |
                (unsigned long long)__float_as_uint(acc[q].x);
            __builtin_nontemporal_store(p, out64 + row * 64 + lane);
        }
    }
}

// ---------- Fallback: direct atomic scatter-add ----------
__global__ void k_atomic(const int* __restrict__ rows, const int* __restrict__ cols,
                         const float* __restrict__ vals, const float2* __restrict__ emb,
                         float* __restrict__ out, int E) {
    long long g = (long long)blockIdx.x * blockDim.x + threadIdx.x;
    int e    = (int)(g >> 6);
    int lane = (int)(g & 63);
    if (e >= E) return;
    int r = rows[e], c = cols[e];
    float v = vals[e];
    float2 em = emb[(size_t)c * (D / 2) + lane];
    atomicAdd(&out[(size_t)r * D + lane * 2    ], v * em.x);
    atomicAdd(&out[(size_t)r * D + lane * 2 + 1], v * em.y);
}

extern "C" void kernel_launch(void* const* d_in, const int* in_sizes, int n_in,
                              void* d_out, int out_size, void* d_ws, size_t ws_size,
                              hipStream_t stream) {
    const int*   adj  = (const int*)d_in[0];
    const float* vals = (const float*)d_in[1];
    const float* emb  = (const float*)d_in[2];
    int E = in_sizes[1];
    int N = in_sizes[2] / D;
    const int* rows = adj;
    const int* cols = adj + E;
    float* out = (float*)d_out;

    int nb   = (N + BROWS - 1) / BROWS;
    int CE   = (E + CHUNKS - 1) / CHUNKS;
    int flat = nb * CHUNKS;
    int nblk = (flat + 1023) / 1024;

    size_t off_sorted = 0;
    size_t sz_sorted  = (size_t)E * 8;
    size_t off_M      = (off_sorted + sz_sorted + 255) & ~(size_t)255;
    size_t sz_M       = (size_t)flat * 4;
    size_t off_O      = (off_M + sz_M + 255) & ~(size_t)255;
    size_t sz_O       = (size_t)flat * 4;
    size_t off_bs     = (off_O + sz_O + 255) & ~(size_t)255;
    size_t sz_bs      = (size_t)nblk * 4;
    size_t off_q      = (off_bs + sz_bs + 255) & ~(size_t)255;
    size_t sz_q       = (size_t)N * 64 * 4;
    size_t need_bf16  = off_q + sz_q;
    size_t need_f32   = off_q;

    bool ok = (N <= (1 << COLBITS)) && ((size_t)nb * 4 <= 60000) && (nblk <= 1024);

    if (ok && ws_size >= need_f32) {
        char* ws = (char*)d_ws;
        unsigned long long* sorted = (unsigned long long*)(ws + off_sorted);
        int* M  = (int*)(ws + off_M);
        int* O  = (int*)(ws + off_O);
        int* bs = (int*)(ws + off_bs);
        bool bf16 = (ws_size >= need_bf16);
        unsigned* q = (unsigned*)(ws + off_q);

        int cvtb = bf16 ? CVTB : 0;
        k_prep    <<<CHUNKS + cvtb, PBLK, (size_t)nb * 4, stream>>>(
                      rows, E, CE, nb, M, (const float2*)emb, q, N * 64, cvtb);
        k_scan1   <<<nblk, 1024, 0, stream>>>(M, flat, O, bs);
        k_scan2   <<<1, 1024, 0, stream>>>(bs, nblk);
        k_mscatter<<<CHUNKS, PBLK, (size_t)nb * 4, stream>>>(
                      rows, cols, vals, E, CE, nb, O, bs, sorted);
        if (bf16) {
            k_bucket2<true><<<nb, 256, 0, stream>>>((const int2*)sorted, O, bs,
                                                    (const void*)q, out, N, nb, E);
        } else {
            k_bucket2<false><<<nb, 256, 0, stream>>>((const int2*)sorted, O, bs,
                                                     (const void*)emb, out, N, nb, E);
        }
    } else {
        hipMemsetAsync(out, 0, (size_t)out_size * sizeof(float), stream);
        long long tot = (long long)E * 64;
        int blocks = (int)((tot + 255) / 256);
        k_atomic<<<blocks, 256, 0, stream>>>(rows, cols, vals, (const float2*)emb, out, E);
    }
}

// Round 9
// 313.382 us; speedup vs baseline: 1.4558x; 1.0662x over previous
//
#include <hip/hip_runtime.h>

#define D 128
#define BROWS 32
#define BSHIFT 5
#define COLBITS 17
#define COLMASK 0x1FFFF
#define CHUNKS 256
#define CAP 1280
#define CVTB 1792
#define PBLK 1024
// XCD-grouping permutation of chunk->matrix-slot (valid for CHUNKS==256):
// consecutive slots (same cache line) belong to chunks with equal c%8 (same XCD).
#define PERM(c) ((((c) & 7) << 5) | ((c) >> 3))

// ---------- Phase 1 (fused): per-chunk bucket histogram + emb fp32->bf16x2 ----------
// M[b * CHUNKS + PERM(c)] = #edges of chunk c landing in bucket b
__global__ void k_prep(const int* __restrict__ rows, int E, int CE, int nb,
                       int* __restrict__ M,
                       const float2* __restrict__ emb, unsigned* __restrict__ q,
                       int n, int cvtb) {
    int histBlocks = gridDim.x - cvtb;
    if ((int)blockIdx.x >= histBlocks) {
        int stride = cvtb * PBLK;
        for (int i = ((int)blockIdx.x - histBlocks) * PBLK + threadIdx.x; i < n; i += stride) {
            float2 f = emb[i];
            unsigned lo = __float_as_uint(f.x), hi = __float_as_uint(f.y);
            lo = (lo + 0x7FFFu + ((lo >> 16) & 1u)) & 0xFFFF0000u;   // RNE to bf16
            hi = (hi + 0x7FFFu + ((hi >> 16) & 1u)) & 0xFFFF0000u;
            q[i] = hi | (lo >> 16);
        }
        return;
    }
    extern __shared__ int h[];
    int c = blockIdx.x;
    int slot = PERM(c);
    for (int i = threadIdx.x; i < nb; i += PBLK) h[i] = 0;
    __syncthreads();
    int beg = c * CE, end = min(E, beg + CE);
    for (int e = beg + threadIdx.x; e < end; e += PBLK)
        atomicAdd(&h[rows[e] >> BSHIFT], 1);
    __syncthreads();
    for (int i = threadIdx.x; i < nb; i += PBLK) M[(size_t)i * CHUNKS + slot] = h[i];
}

// ---------- Phase 2: hierarchical exclusive scan (block-local O + block sums bs) ----------
__global__ void k_scan1(const int* __restrict__ M, int flat,
                        int* __restrict__ O, int* __restrict__ bs) {
    __shared__ int s[1024];
    int i = blockIdx.x * 1024 + threadIdx.x;
    int v = (i < flat) ? M[i] : 0;
    s[threadIdx.x] = v;
    __syncthreads();
    for (int off = 1; off < 1024; off <<= 1) {
        int t = (threadIdx.x >= (unsigned)off) ? s[threadIdx.x - off] : 0;
        __syncthreads();
        s[threadIdx.x] += t;
        __syncthreads();
    }
    if (i < flat) O[i] = s[threadIdx.x] - v;
    if (threadIdx.x == 1023) bs[blockIdx.x] = s[1023];
}

__global__ void k_scan2(int* __restrict__ bs, int nblk) {
    __shared__ int s[1024];
    __shared__ int carry;
    if (threadIdx.x == 0) carry = 0;
    __syncthreads();
    for (int base = 0; base < nblk; base += 1024) {
        int i = base + (int)threadIdx.x;
        int v = (i < nblk) ? bs[i] : 0;
        s[threadIdx.x] = v;
        __syncthreads();
        for (int off = 1; off < 1024; off <<= 1) {
            int t = (threadIdx.x >= (unsigned)off) ? s[threadIdx.x - off] : 0;
            __syncthreads();
            s[threadIdx.x] += t;
            __syncthreads();
        }
        int c = carry;
        if (i < nblk) bs[i] = c + s[threadIdx.x] - v;
        __syncthreads();
        if (threadIdx.x == 0) carry = c + s[1023];
        __syncthreads();
    }
}

// ---------- Phase 3: scatter via LDS cursors; final offset = O[f] + bs[f>>10] ----------
__global__ void k_mscatter(const int* __restrict__ rows, const int* __restrict__ cols,
                           const float* __restrict__ vals, int E, int CE, int nb,
                           const int* __restrict__ O, const int* __restrict__ bs,
                           unsigned long long* __restrict__ sorted) {
    extern __shared__ int cur[];
    int c = blockIdx.x;
    int slot = PERM(c);
    for (int b = threadIdx.x; b < nb; b += PBLK) {
        int f = b * CHUNKS + slot;
        cur[b] = O[f] + bs[f >> 10];
    }
    __syncthreads();
    int beg = c * CE, end = min(E, beg + CE);
    for (int e = beg + threadIdx.x; e < end; e += PBLK) {
        int r = rows[e];
        int b = r >> BSHIFT;
        int pos = atomicAdd(&cur[b], 1);
        unsigned packed = ((unsigned)(r & (BROWS - 1)) << COLBITS) | (unsigned)cols[e];
        unsigned long long rec =
            ((unsigned long long)__float_as_uint(vals[e]) << 32) | (unsigned long long)packed;
        if (pos >= 0 && pos < E)                     // normal store: L2 aggregates lines
            sorted[pos] = rec;
    }
}

// ---------- Phase 4: per-bucket LDS counting sort + REGISTER accumulation ----------
#define GATHER(idx) \
    int2 r##idx = rec2[off + j + idx]; \
    float v##idx = __int_as_float(r##idx.y);

template <bool BF16>
__global__ __launch_bounds__(256) void k_bucket2(const int2* __restrict__ sorted,
                                                 const int* __restrict__ O,
                                                 const int* __restrict__ bs,
                                                 const void* __restrict__ embp,
                                                 float* __restrict__ out,
                                                 int N, int nb, int E) {
    __shared__ int rowcnt[BROWS], rowoff[BROWS], rowcur[BROWS];
    __shared__ int2 rec2[CAP];
    int b  = blockIdx.x;
    int f0 = b * CHUNKS;                 // PERM(0)==0: still the bucket's first slot
    int beg = O[f0] + bs[f0 >> 10];
    int end;
    if (b + 1 < nb) { int f1 = (b + 1) * CHUNKS; end = O[f1] + bs[f1 >> 10]; }
    else            end = E;
    beg = max(0, min(beg, E));
    end = max(beg, min(end, E));
    int wid = threadIdx.x >> 6, lane = threadIdx.x & 63;

    float2 acc[8];
#pragma unroll
    for (int q = 0; q < 8; ++q) acc[q] = make_float2(0.f, 0.f);

    const unsigned* eq = (const unsigned*)embp;
    const float2*   e2 = (const float2*)embp;

    for (int done = beg; done < end; done += CAP) {
        int cnt = min(CAP, end - done);
        if (threadIdx.x < BROWS) rowcnt[threadIdx.x] = 0;
        __syncthreads();
        for (int k = threadIdx.x; k < cnt; k += 256)
            atomicAdd(&rowcnt[(((unsigned)sorted[done + k].x) >> COLBITS) & (BROWS - 1)], 1);
        __syncthreads();
        if (threadIdx.x < BROWS) {
            int v = rowcnt[threadIdx.x];
            int incl = v;
#pragma unroll
            for (int off = 1; off < BROWS; off <<= 1) {
                int u = __shfl_up(incl, off);
                if ((int)threadIdx.x >= off) incl += u;
            }
            rowoff[threadIdx.x] = incl - v;
            rowcur[threadIdx.x] = incl - v;
        }
        __syncthreads();
        for (int k = threadIdx.x; k < cnt; k += 256) {
            int2 r = sorted[done + k];
            int row = (((unsigned)r.x) >> COLBITS) & (BROWS - 1);
            int pos = atomicAdd(&rowcur[row], 1);
            if (pos >= 0 && pos < CAP) rec2[pos] = r;
        }
        __syncthreads();

#pragma unroll
        for (int q = 0; q < 8; ++q) {            // 8 rows/wave: acc stays in VGPRs
            int row = wid * 8 + q;
            int off = rowoff[row], cr = rowcnt[row];
            int j = 0;
            for (; j + 8 <= cr; j += 8) {        // 8 outstanding gathers
                GATHER(0) GATHER(1) GATHER(2) GATHER(3)
                GATHER(4) GATHER(5) GATHER(6) GATHER(7)
                if (BF16) {
                    unsigned u0 = eq[(size_t)(r0.x & COLMASK) * 64 + lane];
                    unsigned u1 = eq[(size_t)(r1.x & COLMASK) * 64 + lane];
                    unsigned u2 = eq[(size_t)(r2.x & COLMASK) * 64 + lane];
                    unsigned u3 = eq[(size_t)(r3.x & COLMASK) * 64 + lane];
                    unsigned u4 = eq[(size_t)(r4.x & COLMASK) * 64 + lane];
                    unsigned u5 = eq[(size_t)(r5.x & COLMASK) * 64 + lane];
                    unsigned u6 = eq[(size_t)(r6.x & COLMASK) * 64 + lane];
                    unsigned u7 = eq[(size_t)(r7.x & COLMASK) * 64 + lane];
                    acc[q].x += v0 * __uint_as_float(u0 << 16);
                    acc[q].y += v0 * __uint_as_float(u0 & 0xFFFF0000u);
                    acc[q].x += v1 * __uint_as_float(u1 << 16);
                    acc[q].y += v1 * __uint_as_float(u1 & 0xFFFF0000u);
                    acc[q].x += v2 * __uint_as_float(u2 << 16);
                    acc[q].y += v2 * __uint_as_float(u2 & 0xFFFF0000u);
                    acc[q].x += v3 * __uint_as_float(u3 << 16);
                    acc[q].y += v3 * __uint_as_float(u3 & 0xFFFF0000u);
                    acc[q].x += v4 * __uint_as_float(u4 << 16);
                    acc[q].y += v4 * __uint_as_float(u4 & 0xFFFF0000u);
                    acc[q].x += v5 * __uint_as_float(u5 << 16);
                    acc[q].y += v5 * __uint_as_float(u5 & 0xFFFF0000u);
                    acc[q].x += v6 * __uint_as_float(u6 << 16);
                    acc[q].y += v6 * __uint_as_float(u6 & 0xFFFF0000u);
                    acc[q].x += v7 * __uint_as_float(u7 << 16);
                    acc[q].y += v7 * __uint_as_float(u7 & 0xFFFF0000u);
                } else {
                    float2 e0 = e2[(size_t)(r0.x & COLMASK) * 64 + lane];
                    float2 e1 = e2[(size_t)(r1.x & COLMASK) * 64 + lane];
                    float2 e2v = e2[(size_t)(r2.x & COLMASK) * 64 + lane];
                    float2 e3 = e2[(size_t)(r3.x & COLMASK) * 64 + lane];
                    float2 e4 = e2[(size_t)(r4.x & COLMASK) * 64 + lane];
                    float2 e5 = e2[(size_t)(r5.x & COLMASK) * 64 + lane];
                    float2 e6 = e2[(size_t)(r6.x & COLMASK) * 64 + lane];
                    float2 e7 = e2[(size_t)(r7.x & COLMASK) * 64 + lane];
                    acc[q].x += v0 * e0.x;  acc[q].y += v0 * e0.y;
                    acc[q].x += v1 * e1.x;  acc[q].y += v1 * e1.y;
                    acc[q].x += v2 * e2v.x; acc[q].y += v2 * e2v.y;
                    acc[q].x += v3 * e3.x;  acc[q].y += v3 * e3.y;
                    acc[q].x += v4 * e4.x;  acc[q].y += v4 * e4.y;
                    acc[q].x += v5 * e5.x;  acc[q].y += v5 * e5.y;
                    acc[q].x += v6 * e6.x;  acc[q].y += v6 * e6.y;
                    acc[q].x += v7 * e7.x;  acc[q].y += v7 * e7.y;
                }
            }
            for (; j < cr; ++j) {
                int2 r0 = rec2[off + j];
                float v0 = __int_as_float(r0.y);
                if (BF16) {
                    unsigned u0 = eq[(size_t)(r0.x & COLMASK) * 64 + lane];
                    acc[q].x += v0 * __uint_as_float(u0 << 16);
                    acc[q].y += v0 * __uint_as_float(u0 & 0xFFFF0000u);
                } else {
                    float2 e0 = e2[(size_t)(r0.x & COLMASK) * 64 + lane];
                    acc[q].x += v0 * e0.x;
                    acc[q].y += v0 * e0.y;
                }
            }
        }
        __syncthreads();
    }

    // nontemporal output stores: out is never re-read; keep L2 for emb gathers
    size_t rowbase = (size_t)b * BROWS;
    unsigned long long* out64 = (unsigned long long*)out;
#pragma unroll
    for (int q = 0; q < 8; ++q) {
        size_t row = rowbase + wid * 8 + q;
        if (row < (size_t)N) {
            unsigned long long p =
                ((unsigned long long)__float_as_uint(acc[q].y) << 32) |
                (unsigned long long)__float_as_uint(acc[q].x);
            __builtin_nontemporal_store(p, out64 + row * 64 + lane);
        }
    }
}

// ---------- Fallback: direct atomic scatter-add ----------
__global__ void k_atomic(const int* __restrict__ rows, const int* __restrict__ cols,
                         const float* __restrict__ vals, const float2* __restrict__ emb,
                         float* __restrict__ out, int E) {
    long long g = (long long)blockIdx.x * blockDim.x + threadIdx.x;
    int e    = (int)(g >> 6);
    int lane = (int)(g & 63);
    if (e >= E) return;
    int r = rows[e], c = cols[e];
    float v = vals[e];
    float2 em = emb[(size_t)c * (D / 2) + lane];
    atomicAdd(&out[(size_t)r * D + lane * 2    ], v * em.x);
    atomicAdd(&out[(size_t)r * D + lane * 2 + 1], v * em.y);
}

extern "C" void kernel_launch(void* const* d_in, const int* in_sizes, int n_in,
                              void* d_out, int out_size, void* d_ws, size_t ws_size,
                              hipStream_t stream) {
    const int*   adj  = (const int*)d_in[0];
    const float* vals = (const float*)d_in[1];
    const float* emb  = (const float*)d_in[2];
    int E = in_sizes[1];
    int N = in_sizes[2] / D;
    const int* rows = adj;
    const int* cols = adj + E;
    float* out = (float*)d_out;

    int nb   = (N + BROWS - 1) / BROWS;
    int CE   = (E + CHUNKS - 1) / CHUNKS;
    int flat = nb * CHUNKS;
    int nblk = (flat + 1023) / 1024;

    size_t off_sorted = 0;
    size_t sz_sorted  = (size_t)E * 8;
    size_t off_M      = (off_sorted + sz_sorted + 255) & ~(size_t)255;
    size_t sz_M       = (size_t)flat * 4;
    size_t off_O      = (off_M + sz_M + 255) & ~(size_t)255;
    size_t sz_O       = (size_t)flat * 4;
    size_t off_bs     = (off_O + sz_O + 255) & ~(size_t)255;
    size_t sz_bs      = (size_t)nblk * 4;
    size_t off_q      = (off_bs + sz_bs + 255) & ~(size_t)255;
    size_t sz_q       = (size_t)N * 64 * 4;
    size_t need_bf16  = off_q + sz_q;
    size_t need_f32   = off_q;

    bool ok = (N <= (1 << COLBITS)) && ((size_t)nb * 4 <= 60000) && (nblk <= 1024);

    if (ok && ws_size >= need_f32) {
        char* ws = (char*)d_ws;
        unsigned long long* sorted = (unsigned long long*)(ws + off_sorted);
        int* M  = (int*)(ws + off_M);
        int* O  = (int*)(ws + off_O);
        int* bs = (int*)(ws + off_bs);
        bool bf16 = (ws_size >= need_bf16);
        unsigned* q = (unsigned*)(ws + off_q);

        int cvtb = bf16 ? CVTB : 0;
        k_prep    <<<CHUNKS + cvtb, PBLK, (size_t)nb * 4, stream>>>(
                      rows, E, CE, nb, M, (const float2*)emb, q, N * 64, cvtb);
        k_scan1   <<<nblk, 1024, 0, stream>>>(M, flat, O, bs);
        k_scan2   <<<1, 1024, 0, stream>>>(bs, nblk);
        k_mscatter<<<CHUNKS, PBLK, (size_t)nb * 4, stream>>>(
                      rows, cols, vals, E, CE, nb, O, bs, sorted);
        if (bf16) {
            k_bucket2<true><<<nb, 256, 0, stream>>>((const int2*)sorted, O, bs,
                                                    (const void*)q, out, N, nb, E);
        } else {
            k_bucket2<false><<<nb, 256, 0, stream>>>((const int2*)sorted, O, bs,
                                                     (const void*)emb, out, N, nb, E);
        }
    } else {
        hipMemsetAsync(out, 0, (size_t)out_size * sizeof(float), stream);
        long long tot = (long long)E * 64;
        int blocks = (int)((tot + 255) / 256);
        k_atomic<<<blocks, 256, 0, stream>>>(rows, cols, vals, (const float2*)emb, out, E);
    }
}